// Round 1
// baseline (63.514 us; speedup 1.0000x reference)
//
#include <hip/hip_runtime.h>

// Problem constants (from reference):
#define BB 8
#define NN 32768
#define CC 4
#define MM 11          // memory length (FIR taps)
#define DD 5           // polynomial degree count (amp^0..amp^4)
#define KK 55          // D*M
#define BLOCK_N 256
#define HALO (MM - 1)          // 10
#define SS (BLOCK_N + HALO)    // 266 staged samples per block

// out[b,c,n] = sum_{j=0..10} z[n-10+j] * ( sum_d W[c, d*11+j] * |z[n-10+j]|^d )
// z[t] = x[b,t,c,0] + i x[b,t,c,1], zero for t<0.

__global__ __launch_bounds__(256, 4)
void gmp_kernel(const float* __restrict__ x,
                const float* __restrict__ W,
                float* __restrict__ out) {
    // Per staged sample: lo = ch0/ch1 (re,im,re,im), hi = ch2/ch3, amp4 = |z| per channel.
    // 48 B per sample -> lane stride 12 dwords -> conflict-optimal ds_read_b128.
    __shared__ float4 smem[SS * 3];

    const int tid = threadIdx.x;
    const int b = blockIdx.y;
    const int n0 = blockIdx.x * BLOCK_N;

    const float4* xg = (const float4*)x + (size_t)b * NN * 2;

    // Stage samples t = n0-10 .. n0+255 (zero-fill t<0), compute amp once per sample.
    for (int s = tid; s < SS; s += BLOCK_N) {
        const int t = n0 - HALO + s;
        float4 lo = make_float4(0.f, 0.f, 0.f, 0.f);
        float4 hi = lo;
        if (t >= 0) {
            lo = xg[2 * t];
            hi = xg[2 * t + 1];
        }
        float4 a;
        a.x = sqrtf(fmaf(lo.x, lo.x, lo.y * lo.y));
        a.y = sqrtf(fmaf(lo.z, lo.z, lo.w * lo.w));
        a.z = sqrtf(fmaf(hi.x, hi.x, hi.y * hi.y));
        a.w = sqrtf(fmaf(hi.z, hi.z, hi.w * hi.w));
        smem[s * 3 + 0] = lo;
        smem[s * 3 + 1] = hi;
        smem[s * 3 + 2] = a;
    }
    __syncthreads();

    float acc_re[CC] = {0.f, 0.f, 0.f, 0.f};
    float acc_im[CC] = {0.f, 0.f, 0.f, 0.f};

    #pragma unroll
    for (int j = 0; j < MM; j++) {
        const int s = tid + j;   // sample t = n-10+j
        const float4 lo = smem[s * 3 + 0];
        const float4 hi = smem[s * 3 + 1];
        const float4 a  = smem[s * 3 + 2];
        const float re[CC] = {lo.x, lo.z, hi.x, hi.z};
        const float im[CC] = {lo.y, lo.w, hi.y, hi.w};
        const float am[CC] = {a.x, a.y, a.z, a.w};
        #pragma unroll
        for (int c = 0; c < CC; c++) {
            // Horner over amp powers; W offsets are compile-time -> scalar loads.
            float p = W[c * KK + 4 * MM + j];
            p = fmaf(p, am[c], W[c * KK + 3 * MM + j]);
            p = fmaf(p, am[c], W[c * KK + 2 * MM + j]);
            p = fmaf(p, am[c], W[c * KK + 1 * MM + j]);
            p = fmaf(p, am[c], W[c * KK + 0 * MM + j]);
            acc_re[c] = fmaf(re[c], p, acc_re[c]);
            acc_im[c] = fmaf(im[c], p, acc_im[c]);
        }
    }

    // out[b,n,c,{re,im}] -> 8 contiguous floats per (b,n).
    const int n = n0 + tid;
    float4* og = (float4*)out + (size_t)(b * NN + n) * 2;
    og[0] = make_float4(acc_re[0], acc_im[0], acc_re[1], acc_im[1]);
    og[1] = make_float4(acc_re[2], acc_im[2], acc_re[3], acc_im[3]);
}

extern "C" void kernel_launch(void* const* d_in, const int* in_sizes, int n_in,
                              void* d_out, int out_size, void* d_ws, size_t ws_size,
                              hipStream_t stream) {
    const float* x = (const float*)d_in[0];   // [B,N,C,2] fp32
    const float* W = (const float*)d_in[1];   // [C,K] fp32
    float* out = (float*)d_out;               // [B,N,C,2] fp32

    dim3 grid(NN / BLOCK_N, BB);
    gmp_kernel<<<grid, BLOCK_N, 0, stream>>>(x, W, out);
}